// Round 5
// baseline (2851.914 us; speedup 1.0000x reference)
//
#include <hip/hip_runtime.h>
#include <hip/hip_bf16.h>

// Problem constants (GraphGRUCell_62019327754706)
// DTYPE (settled round 4->5): inputs FP32 (bf16-misread gave NaN; fp32 read
// finite). OUTPUT is FP32 — reference returns jnp.float32; harness doc says
// d_out is the reference's output dtype. Round 4's 5.5 error was bf16 ushorts
// packed into an fp32 buffer.
#define BB 4
#define NN 20000
#define UU 64
#define EE 640000
#define FF 65              // U + D
#define SCALE_F 0.125f     // 1/sqrt(64)
#define NEG_F  -1e30f

static inline size_t align_up(size_t x) { return (x + 255) & ~(size_t)255; }

// ---------------------------------------------------------------- CSR build
__global__ __launch_bounds__(256) void hist_kernel(const int* __restrict__ edst,
                                                   int* __restrict__ counts) {
    int e = blockIdx.x * 256 + threadIdx.x;
    if (e < EE) {
        int d = edst[e];
        if ((unsigned)d < (unsigned)NN) atomicAdd(&counts[d], 1);
    }
}

__global__ __launch_bounds__(1024) void scan_kernel(const int* __restrict__ counts,
                                                    int* __restrict__ off,
                                                    int* __restrict__ cursor) {
    __shared__ int sd[1024];
    __shared__ int carry_s;
    int tid = threadIdx.x;
    if (tid == 0) carry_s = 0;
    __syncthreads();
    for (int base = 0; base < NN; base += 1024) {
        int i = base + tid;
        int val = (i < NN) ? counts[i] : 0;
        sd[tid] = val;
        __syncthreads();
        for (int d = 1; d < 1024; d <<= 1) {   // Hillis-Steele inclusive scan
            int t = (tid >= d) ? sd[tid - d] : 0;
            __syncthreads();
            sd[tid] += t;
            __syncthreads();
        }
        int incl = sd[tid];
        int excl = carry_s + incl - val;
        if (i < NN) { off[i] = excl; cursor[i] = excl; }
        __syncthreads();
        if (tid == 1023) carry_s += sd[1023];
        __syncthreads();
    }
    if (tid == 0) off[NN] = carry_s;           // == EE
}

__global__ __launch_bounds__(256) void scatter_kernel(const int* __restrict__ edst,
                                                      const int* __restrict__ esrc,
                                                      int* __restrict__ cursor,
                                                      int* __restrict__ psrc) {
    int e = blockIdx.x * 256 + threadIdx.x;
    if (e < EE) {
        int d = edst[e];
        if ((unsigned)d < (unsigned)NN) {
            int p = atomicAdd(&cursor[d], 1);
            if ((unsigned)p < (unsigned)EE) psrc[p] = esrc[e];
        }
    }
}

// ------------------------- fully fused: proj + softmax-agg (kv-free) + GRU
// One wave per (b,n). lane = channel u.
// score(d,s) = qk . h_s + qk64*xin_s + q.bk   where qk[f] = sum_u Wk[f][u] q[u]
// (q pre-scaled by 1/8);  agg = (Wv^T (sum p_s x_s)) / l + bv
__global__ __launch_bounds__(256) void fused_kernel(
    const float* __restrict__ state, const float* __restrict__ inputs,
    const float* __restrict__ Wq, const float* __restrict__ bq,
    const float* __restrict__ Wk, const float* __restrict__ bk,
    const float* __restrict__ Wv, const float* __restrict__ bv,
    const float* __restrict__ Ws, const float* __restrict__ bs,
    const float* __restrict__ W1, const float* __restrict__ b1,
    const float* __restrict__ W2, const float* __restrict__ b2,
    const int* __restrict__ off, const int* __restrict__ psrc,
    float* __restrict__ out) {
    int w = threadIdx.x >> 6, lane = threadIdx.x & 63;
    int g = blockIdx.x * 4 + w;               // g = b*NN + n
    int b = g / NN, n = g - b * NN;
    size_t o = (size_t)g * UU + lane;
    __shared__ float xsL[4][FF];
    __shared__ float qsL[4][UU];
    __shared__ float xaL[4][UU];
    __shared__ float h2L[4][UU];

    float hval = state[o];
    float xinv = inputs[g];
    xsL[w][lane] = hval;
    if (lane == 0) xsL[w][UU] = xinv;
    __syncthreads();                          // sync1 (uniform)

    // q (pre-scaled) and x@Ws + bs
    float aq = 0.f, as_ = 0.f;
    for (int f = 0; f < FF; ++f) {
        float xv = xsL[w][f];
        aq  += xv * Wq[f * UU + lane];
        as_ += xv * Ws[f * UU + lane];
    }
    aq = (aq + bq[lane]) * SCALE_F;           // pow2 scale: exact
    as_ += bs[lane];
    qsL[w][lane] = aq;
    __syncthreads();                          // sync2 (uniform)

    // qk[lane] = sum_u Wk[lane][u] * q[u]; uniform terms qk64, q.bk
    float qk = 0.f;
    for (int u = 0; u < UU; ++u)
        qk += Wk[lane * UU + u] * qsL[w][u];
    float qk64 = 0.f, qbk = 0.f;
    for (int u = 0; u < UU; ++u) {
        float qu = qsL[w][u];
        qk64 += Wk[UU * UU + u] * qu;         // Wk row 64 (xin row)
        qbk  += bk[u] * qu;
    }

    bool mg = (__shfl(hval, 58, 64) != 0.0f); // node mask x[...,-7], wave-uniform

    // online softmax over incoming edges (no barriers inside)
    float m = NEG_F, l = 0.f, xau = 0.f, xax = 0.f;
    if (mg) {
        int i0 = off[n], i1 = off[n + 1];
        i0 = max(0, min(i0, EE));
        i1 = max(i0, min(i1, EE));
        const float* stb = state  + (size_t)b * NN * UU;
        const float* inb = inputs + (size_t)b * NN;
        for (int i = i0; i < i1; ++i) {
            int s = psrc[i];                  // wave-uniform
            if ((unsigned)s >= (unsigned)NN) continue;
            float hsu = stb[(size_t)s * UU + lane];
            if (__shfl(hsu, 58, 64) == 0.0f) continue;   // masked src
            float xins = inb[s];
            float t = qk * hsu;
#pragma unroll
            for (int d = 1; d < 64; d <<= 1) t += __shfl_xor(t, d, 64);
            t += qk64 * xins + qbk;           // full scaled score
            float mn = fmaxf(m, t);
            float cs = __expf(m - mn);        // m==NEG_F -> 0
            float p  = __expf(t - mn);
            l   = l   * cs + p;
            xau = xau * cs + p * hsu;
            xax = xax * cs + p * xins;
            m = mn;
        }
    }
    xaL[w][lane] = xau;
    __syncthreads();                          // sync3 (uniform)

    float h2;
    if (mg) {
        float agg = 0.f;
        if (l > 0.f) {
            float num = 0.f;
            for (int f = 0; f < UU; ++f)
                num += Wv[f * UU + lane] * xaL[w][f];
            num += Wv[UU * UU + lane] * xax;
            agg = num / fmaxf(l, 1e-16f) + bv[lane];
        }
        h2 = agg + as_;
    } else {
        h2 = hval;                            // masked node: pass-through h
    }

    h2L[w][lane] = h2;
    __syncthreads();                          // sync4 (uniform)

    // value = sigmoid([xin, h2] @ W1 + b1); lane computes cols lane, 64+lane
    float a1 = xinv * W1[lane];
    float a2 = xinv * W1[UU + lane];
    for (int f = 0; f < UU; ++f) {
        float hv = h2L[w][f];
        a1 += hv * W1[(f + 1) * 128 + lane];
        a2 += hv * W1[(f + 1) * 128 + UU + lane];
    }
    a1 += b1[lane];
    a2 += b1[UU + lane];
    float reset = 1.f / (1.f + __expf(-a1));
    float z     = 1.f / (1.f + __expf(-a2));

    __syncthreads();                          // sync5 (uniform, before overwrite)
    h2L[w][lane] = reset * h2;
    __syncthreads();                          // sync6 (uniform)

    // c = tanh([xin, reset*h2] @ W2 + b2)
    float a3 = xinv * W2[lane];
    for (int f = 0; f < UU; ++f)
        a3 += h2L[w][f] * W2[(f + 1) * UU + lane];
    a3 += b2[lane];
    float aa = fabsf(a3);
    float tt = __expf(-2.f * aa);
    float c  = copysignf((1.f - tt) / (1.f + tt), a3);  // overflow-safe tanh

    out[o] = (1.f - z) * h2 + z * c;          // FP32 store (d_out is float*)
}

// ------------------------------------------------------------------- launch
extern "C" void kernel_launch(void* const* d_in, const int* in_sizes, int n_in,
                              void* d_out, int out_size, void* d_ws, size_t ws_size,
                              hipStream_t stream) {
    // inputs (B*N) vs state (B*N*U): disambiguate by size for robustness
    const float* inputs = (const float*)d_in[0];
    const float* state  = (const float*)d_in[1];
    if (in_sizes[0] != BB * NN) { inputs = (const float*)d_in[1]; state = (const float*)d_in[0]; }
    const int*   esrc   = (const int*)d_in[2];
    const int*   edst   = (const int*)d_in[3];
    const float* Wq = (const float*)d_in[4];
    const float* bq = (const float*)d_in[5];
    const float* Wk = (const float*)d_in[6];
    const float* bk = (const float*)d_in[7];
    const float* Wv = (const float*)d_in[8];
    const float* bv = (const float*)d_in[9];
    const float* Ws = (const float*)d_in[10];
    const float* bs = (const float*)d_in[11];
    const float* W1 = (const float*)d_in[12];
    const float* b1 = (const float*)d_in[13];
    const float* W2 = (const float*)d_in[14];
    const float* b2 = (const float*)d_in[15];
    float* out = (float*)d_out;

    // workspace carve — CSR only, ~2.8 MB total
    char* base = (char*)d_ws;
    size_t ofs = 0;
    int* counts = (int*)(base + ofs); ofs = align_up(ofs + (size_t)NN * 4);
    int* offp   = (int*)(base + ofs); ofs = align_up(ofs + (size_t)(NN + 1) * 4);
    int* cursor = (int*)(base + ofs); ofs = align_up(ofs + (size_t)NN * 4);
    int* psrc   = (int*)(base + ofs); ofs = align_up(ofs + (size_t)EE * 4);
    (void)ws_size; (void)n_in; (void)out_size;

    hipMemsetAsync(counts, 0, (size_t)NN * 4, stream);
    hist_kernel<<<(EE + 255) / 256, 256, 0, stream>>>(edst, counts);
    scan_kernel<<<1, 1024, 0, stream>>>(counts, offp, cursor);
    scatter_kernel<<<(EE + 255) / 256, 256, 0, stream>>>(edst, esrc, cursor, psrc);

    int nodeBlocks = (BB * NN) / 4;   // 20000 blocks, 4 waves each
    fused_kernel<<<nodeBlocks, 256, 0, stream>>>(state, inputs, Wq, bq, Wk, bk,
                                                 Wv, bv, Ws, bs, W1, b1, W2, b2,
                                                 offp, psrc, out);
}